// Round 12
// baseline (88.092 us; speedup 1.0000x reference)
//
#include <hip/hip_runtime.h>
#include <hip/hip_bf16.h>
#include <math.h>

#define B_ 256
#define G_ 4000
#define P_ 128
#define D_ 12000
#define H_ 64
#define O_ 16
#define GH_ 128
#define CH_ 8
#define C_ 5
#define K_ 3
#define EPS_ 1e-5f
#define KCH_ 500    // gate gemm1: K-chunk per tile
#define KIN_ 100    // gate gemm1: inner K tile in LDS
#define CAP_ 640    // compacted row capacity per pathway (n_p ~ 400 +- 20)
#define HT_ 320     // expert half-tile (covers ceil(CAP/2))

__device__ __forceinline__ float bf_lo(unsigned int u) {
  return __uint_as_float(u << 16);
}
__device__ __forceinline__ float bf_hi(unsigned int u) {
  return __uint_as_float(u & 0xffff0000u);
}

// ---------------------------------------------------------------------------
// K1: blocks [0,128): compaction of pathway p THEN bf16 plane copy of p's
//                     active rows (same block; copy overlaps other blocks'
//                     gemm1 work instead of serializing as its own kernel).
//     blocks [128,384): gate GEMM1 partial tiles -> hpart (R5-proven).
// ---------------------------------------------------------------------------
__global__ __launch_bounds__(512) void k_pre(const float* __restrict__ gene_mask,
                                             const float* __restrict__ x_rna,
                                             const float* __restrict__ gw1,
                                             const float* __restrict__ W1,
                                             int* __restrict__ cnt,
                                             int* __restrict__ gindex,
                                             unsigned short* __restrict__ wcomp,
                                             float* __restrict__ hpart) {
  int t = threadIdx.x;

  if (blockIdx.x < P_) {
    int p = blockIdx.x;
    int lane = t & 63;
    int w = t >> 6;
    __shared__ int wcnt[8];
    int* lp = gindex + (size_t)p * G_;
    const int per = (G_ + 7) / 8;   // 500
    int start = w * per;
    int end = start + per; if (end > G_) end = G_;

    int count = 0;
    for (int g0 = start; g0 < end; g0 += 64) {
      int g = g0 + lane;
      bool act = (g < end) && (gene_mask[(size_t)g * P_ + p] != 0.0f);
      count += __popcll(__ballot(act));
    }
    if (lane == 0) wcnt[w] = count;
    __syncthreads();
    if (t == 0) {
      int tot = 0;
      for (int i = 0; i < 8; ++i) tot += wcnt[i];
      cnt[p] = tot;
    }
    int base = 0;
    for (int i = 0; i < w; ++i) base += wcnt[i];
    for (int g0 = start; g0 < end; g0 += 64) {
      int g = g0 + lane;
      bool act = (g < end) && (gene_mask[(size_t)g * P_ + p] != 0.0f);
      unsigned long long bal = __ballot(act);
      int rank = __popcll(bal & ((1ull << lane) - 1ull));
      if (act) lp[base + rank] = g;
      base += __popcll(bal);
    }
    __syncthreads();                 // gindex/cnt writes drained & visible

    // ---- bf16 plane copy for pathway p: wave w copies rows w, w+8, ... ----
    int n = cnt[p];
    if (n > CAP_) n = CAP_;          // overflow served by expert f32 tail
#pragma unroll
    for (int o = 0; o < 3; ++o) {
      const float* src = W1 + ((size_t)p * D_ + (size_t)o * G_) * H_;
      unsigned short* dst = wcomp + (size_t)(p * 3 + o) * CAP_ * H_;
      for (int gi = w; gi < n; gi += 8) {
        int g = lp[gi];
        float f = src[(size_t)g * H_ + lane];
        __hip_bfloat16 bv = __float2bfloat16(f);
        dst[(size_t)gi * H_ + lane] = *(unsigned short*)&bv;
      }
    }
    return;
  }

  // ---- gate GEMM1 partial tile ----
  int idx = blockIdx.x - P_;        // 0..255
  int bt = idx >> 5;                // 8 b-tiles of 32
  int sub = idx & 31;
  int jt = sub >> 3;                // 4 j-tiles of 32
  int kc = sub & 7;                 // 8 k-chunks of 500
  int b0 = bt * 32;
  int j0 = jt * 32;

  __shared__ float xa[32 * KIN_];
  __shared__ float wa[KIN_ * 32];
  float2* wa2 = (float2*)wa;

  int bi = t >> 4;
  int jp = t & 15;
  float2 acc = {0.f, 0.f};

  for (int ch = 0; ch < KCH_ / KIN_; ++ch) {
    int kb = kc * KCH_ + ch * KIN_;
    __syncthreads();
    for (int id = t; id < 32 * KIN_; id += 512) {
      int r = id / KIN_, c = id - r * KIN_;
      xa[id] = x_rna[(size_t)(b0 + r) * G_ + kb + c];
    }
    for (int id = t; id < KIN_ * 32; id += 512) {
      int r = id >> 5, c = id & 31;
      wa[id] = gw1[(size_t)(kb + r) * GH_ + j0 + c];
    }
    __syncthreads();
#pragma unroll 4
    for (int kk = 0; kk < KIN_; ++kk) {
      float x = xa[bi * KIN_ + kk];
      float2 w = wa2[kk * 16 + jp];
      acc.x = fmaf(x, w.x, acc.x);
      acc.y = fmaf(x, w.y, acc.y);
    }
  }
  float2* out = (float2*)(hpart + ((size_t)kc * B_ + (b0 + bi)) * GH_ + j0 + jp * 2);
  *out = acc;
}

// ---------------------------------------------------------------------------
// K2: gate combine + GEMM2 + wave-parallel top-3 + sigmoid (R5-proven).
// ---------------------------------------------------------------------------
__global__ __launch_bounds__(128) void k_gate2(const float* __restrict__ hpart,
                                               const float* __restrict__ gb1,
                                               const float* __restrict__ gw2,
                                               const float* __restrict__ gb2,
                                               float* __restrict__ out_gw,
                                               int* __restrict__ sel_idx,
                                               float* __restrict__ sel_w) {
  int b = blockIdx.x;
  int t = threadIdx.x;

  __shared__ float hid[GH_];
  __shared__ float logitS[P_];
  __shared__ int   s_idx[K_];
  __shared__ float s_val[K_];

  float s = gb1[t];
  for (int kc = 0; kc < 8; ++kc)
    s += hpart[((size_t)kc * B_ + b) * GH_ + t];
  hid[t] = fmaxf(s, 0.f);
  __syncthreads();

  float acc = gb2[t];
  for (int jj = 0; jj < GH_; ++jj)
    acc = fmaf(hid[jj], gw2[(size_t)jj * P_ + t], acc);
  logitS[t] = acc;
  __syncthreads();

  if (t < 64) {
    float v0 = logitS[t], v1 = logitS[t + 64];
    int i0 = t, i1 = t + 64;
    for (int k = 0; k < K_; ++k) {
      float v; int i;
      if (v0 > v1 || (v0 == v1 && i0 < i1)) { v = v0; i = i0; }
      else                                  { v = v1; i = i1; }
      for (int sft = 1; sft < 64; sft <<= 1) {
        float ov = __shfl_xor(v, sft);
        int   oi = __shfl_xor(i, sft);
        if (ov > v || (ov == v && oi < i)) { v = ov; i = oi; }
      }
      if (t == 0) {
        float w = 1.f / (1.f + expf(-v));
        s_idx[k] = i; s_val[k] = w;
        sel_idx[b * K_ + k] = i;
        sel_w[b * K_ + k] = w;
      }
      if (i0 == i) v0 = -INFINITY;
      if (i1 == i) v1 = -INFINITY;
    }
  }
  __syncthreads();

  float gwv = 0.f;
  for (int k = 0; k < K_; ++k) if (s_idx[k] == t) gwv = s_val[k];
  out_gw[(size_t)b * P_ + t] = gwv;
}

// ---------------------------------------------------------------------------
// K3: split expert. 1536 blocks = (bk, gene-half c). Lane = (go,ho); uint4
// bf16 loads (8 rows x 128B per wave-instr). Writes pre-bias partial
// hpart2[bk*2+c][h] (BN/W2/gating/classifier all in K4).
// ---------------------------------------------------------------------------
__global__ __launch_bounds__(512) void k_expert(const float* __restrict__ xr,
                                                const float* __restrict__ xc,
                                                const float* __restrict__ xm,
                                                const float* __restrict__ W1,
                                                const int* __restrict__ cnt,
                                                const int* __restrict__ gindex,
                                                const unsigned short* __restrict__ wcomp,
                                                const int* __restrict__ sel_idx,
                                                float* __restrict__ hpart2) {
  int bk = blockIdx.x >> 1;         // 768
  int c = blockIdx.x & 1;           // gene half
  int b = bk / K_;
  int t = threadIdx.x;
  int w = t >> 6;                   // wave 0..7
  int lane = t & 63;
  int go = lane >> 3;               // gene-octet slot 0..7
  int ho = lane & 7;                // h-octet: h = ho*8..ho*8+7
  int p = sel_idx[bk];
  int n = cnt[p];
  int half = (n + 1) >> 1;
  int c0 = c * half;
  int c1 = c0 + half; if (c1 > n) c1 = n;
  int len = c1 - c0;
  const int* gp = gindex + (size_t)p * G_;
  const unsigned short* Wp = wcomp + (size_t)(p * 3) * CAP_ * H_;
  const float* xrb = xr + (size_t)b * G_;
  const float* xcb = xc + (size_t)b * G_;
  const float* xmb = xm + (size_t)b * G_;

  __shared__ int   glist[HT_];
  __shared__ float xv0[HT_], xv1[HT_], xv2[HT_];
  __shared__ float part[64][H_ + 4];   // ~17.4 KB

  float acc[8];
#pragma unroll
  for (int q = 0; q < 8; ++q) acc[q] = 0.f;

  for (int i = t; i < len; i += 512) {
    int g = gp[c0 + i];
    glist[i] = g;
    xv0[i] = xrb[g]; xv1[i] = xcb[g]; xv2[i] = xmb[g];
  }
  __syncthreads();

  int lenfast = CAP_ - c0;
  if (lenfast > len) lenfast = len;
  if (lenfast < 0) lenfast = 0;
  for (int i0 = w * 8 + go; i0 < lenfast; i0 += 64) {
    size_t off = (size_t)(c0 + i0) * H_ + ho * 8;
    uint4 u0 = *(const uint4*)(Wp + off);
    uint4 u1 = *(const uint4*)(Wp + (size_t)CAP_ * H_ + off);
    uint4 u2 = *(const uint4*)(Wp + (size_t)2 * CAP_ * H_ + off);
    float x0 = xv0[i0], x1 = xv1[i0], x2 = xv2[i0];
    acc[0] = fmaf(x0, bf_lo(u0.x), acc[0]); acc[1] = fmaf(x0, bf_hi(u0.x), acc[1]);
    acc[2] = fmaf(x0, bf_lo(u0.y), acc[2]); acc[3] = fmaf(x0, bf_hi(u0.y), acc[3]);
    acc[4] = fmaf(x0, bf_lo(u0.z), acc[4]); acc[5] = fmaf(x0, bf_hi(u0.z), acc[5]);
    acc[6] = fmaf(x0, bf_lo(u0.w), acc[6]); acc[7] = fmaf(x0, bf_hi(u0.w), acc[7]);
    acc[0] = fmaf(x1, bf_lo(u1.x), acc[0]); acc[1] = fmaf(x1, bf_hi(u1.x), acc[1]);
    acc[2] = fmaf(x1, bf_lo(u1.y), acc[2]); acc[3] = fmaf(x1, bf_hi(u1.y), acc[3]);
    acc[4] = fmaf(x1, bf_lo(u1.z), acc[4]); acc[5] = fmaf(x1, bf_hi(u1.z), acc[5]);
    acc[6] = fmaf(x1, bf_lo(u1.w), acc[6]); acc[7] = fmaf(x1, bf_hi(u1.w), acc[7]);
    acc[0] = fmaf(x2, bf_lo(u2.x), acc[0]); acc[1] = fmaf(x2, bf_hi(u2.x), acc[1]);
    acc[2] = fmaf(x2, bf_lo(u2.y), acc[2]); acc[3] = fmaf(x2, bf_hi(u2.y), acc[3]);
    acc[4] = fmaf(x2, bf_lo(u2.z), acc[4]); acc[5] = fmaf(x2, bf_hi(u2.z), acc[5]);
    acc[6] = fmaf(x2, bf_lo(u2.w), acc[6]); acc[7] = fmaf(x2, bf_hi(u2.w), acc[7]);
  }
  if (lenfast < len) {
    // overflow tail (n > CAP_, ~never): f32 gather, same lane layout
    const float* W1p = W1 + (size_t)p * D_ * H_;
    for (int i0 = w * 8 + go; i0 < len; i0 += 64) {
      if (i0 < lenfast) continue;
      int g = glist[i0];
      const float* r = W1p + (size_t)g * H_ + ho * 8;
      float x0 = xv0[i0], x1 = xv1[i0], x2 = xv2[i0];
      float4 p0 = *(const float4*)r;
      float4 p1 = *(const float4*)(r + 4);
      acc[0] = fmaf(x0, p0.x, acc[0]); acc[1] = fmaf(x0, p0.y, acc[1]);
      acc[2] = fmaf(x0, p0.z, acc[2]); acc[3] = fmaf(x0, p0.w, acc[3]);
      acc[4] = fmaf(x0, p1.x, acc[4]); acc[5] = fmaf(x0, p1.y, acc[5]);
      acc[6] = fmaf(x0, p1.z, acc[6]); acc[7] = fmaf(x0, p1.w, acc[7]);
      const float* r1p = r + (size_t)G_ * H_;
      p0 = *(const float4*)r1p; p1 = *(const float4*)(r1p + 4);
      acc[0] = fmaf(x1, p0.x, acc[0]); acc[1] = fmaf(x1, p0.y, acc[1]);
      acc[2] = fmaf(x1, p0.z, acc[2]); acc[3] = fmaf(x1, p0.w, acc[3]);
      acc[4] = fmaf(x1, p1.x, acc[4]); acc[5] = fmaf(x1, p1.y, acc[5]);
      acc[6] = fmaf(x1, p1.z, acc[6]); acc[7] = fmaf(x1, p1.w, acc[7]);
      const float* r2p = r + (size_t)(2 * G_) * H_;
      p0 = *(const float4*)r2p; p1 = *(const float4*)(r2p + 4);
      acc[0] = fmaf(x2, p0.x, acc[0]); acc[1] = fmaf(x2, p0.y, acc[1]);
      acc[2] = fmaf(x2, p0.z, acc[2]); acc[3] = fmaf(x2, p0.w, acc[3]);
      acc[4] = fmaf(x2, p1.x, acc[4]); acc[5] = fmaf(x2, p1.y, acc[5]);
      acc[6] = fmaf(x2, p1.z, acc[6]); acc[7] = fmaf(x2, p1.w, acc[7]);
    }
  }
  {
    float4 av0 = {acc[0], acc[1], acc[2], acc[3]};
    float4 av1 = {acc[4], acc[5], acc[6], acc[7]};
    *(float4*)&part[w * 8 + go][ho * 8] = av0;
    *(float4*)&part[w * 8 + go][ho * 8 + 4] = av1;
  }
  __syncthreads();

  if (t < H_) {
    float s = 0.f;
#pragma unroll
    for (int ss = 0; ss < 64; ++ss) s += part[ss][t];
    hpart2[(size_t)blockIdx.x * H_ + t] = s;   // pre-bias partial
  }
}

// ---------------------------------------------------------------------------
// K4: fused finish (R4-proven pattern): combine halves + b1 + BN + ReLU + W2
// + gate-weighted sum + classifier. One block (192 thr) per sample.
// ---------------------------------------------------------------------------
__global__ __launch_bounds__(192) void k_final2(const float* __restrict__ hpart2,
                                                const int* __restrict__ sel_idx,
                                                const float* __restrict__ sel_w,
                                                const float* __restrict__ b1,
                                                const float* __restrict__ bn_g,
                                                const float* __restrict__ bn_b,
                                                const float* __restrict__ bn_m,
                                                const float* __restrict__ bn_v,
                                                const float* __restrict__ W2,
                                                const float* __restrict__ b2,
                                                const float* __restrict__ cw1,
                                                const float* __restrict__ cb1,
                                                const float* __restrict__ cw2,
                                                const float* __restrict__ cb2,
                                                float* __restrict__ out_logits) {
  int b = blockIdx.x;
  int t = threadIdx.x;
  int k = t >> 6;
  int h = t & 63;

  __shared__ float hs[K_][H_];
  __shared__ float eoS[K_][O_];
  __shared__ float fs[O_];
  __shared__ float chS[CH_];
  __shared__ int   pS[K_];
  __shared__ float wS[K_];

  int bk = b * K_ + k;
  int p = sel_idx[bk];
  if (h == 0) { pS[k] = p; wS[k] = sel_w[bk]; }

  float s = hpart2[(size_t)(bk * 2) * H_ + h] +
            hpart2[(size_t)(bk * 2 + 1) * H_ + h];
  int ph = p * H_ + h;
  s += b1[ph];
  float hn = (s - bn_m[ph]) * (bn_g[ph] * rsqrtf(bn_v[ph] + EPS_)) + bn_b[ph];
  hs[k][h] = fmaxf(hn, 0.f);
  __syncthreads();

  if (t < K_ * O_) {               // 48 threads
    int k2 = t >> 4;
    int o = t & 15;
    int p2 = pS[k2];
    const float* W2p = W2 + (size_t)p2 * H_ * O_;
    float e = b2[p2 * O_ + o];
    for (int jj = 0; jj < H_; ++jj) e = fmaf(hs[k2][jj], W2p[jj * O_ + o], e);
    eoS[k2][o] = e;
  }
  __syncthreads();

  if (t < O_) {
    float f = 0.f;
    for (int kk = 0; kk < K_; ++kk) f += wS[kk] * eoS[kk][t];
    fs[t] = f;
  }
  __syncthreads();

  if (t < CH_) {
    float a = cb1[t];
    for (int o = 0; o < O_; ++o) a = fmaf(fs[o], cw1[o * CH_ + t], a);
    chS[t] = fmaxf(a, 0.f);
  }
  __syncthreads();

  if (t < C_) {
    float a = cb2[t];
    for (int jj = 0; jj < CH_; ++jj) a = fmaf(chS[jj], cw2[jj * C_ + t], a);
    out_logits[(size_t)b * C_ + t] = a;
  }
}

// ---------------------------------------------------------------------------
extern "C" void kernel_launch(void* const* d_in, const int* in_sizes, int n_in,
                              void* d_out, int out_size, void* d_ws, size_t ws_size,
                              hipStream_t stream) {
  const float* x_rna    = (const float*)d_in[0];
  const float* x_cnv    = (const float*)d_in[1];
  const float* x_met    = (const float*)d_in[2];
  const float* gene_mask= (const float*)d_in[3];
  const float* gate_w1  = (const float*)d_in[4];
  const float* gate_b1  = (const float*)d_in[5];
  const float* gate_w2  = (const float*)d_in[6];
  const float* gate_b2  = (const float*)d_in[7];
  const float* W1       = (const float*)d_in[8];
  const float* b1       = (const float*)d_in[9];
  const float* bn_g     = (const float*)d_in[10];
  const float* bn_b     = (const float*)d_in[11];
  const float* bn_m     = (const float*)d_in[12];
  const float* bn_v     = (const float*)d_in[13];
  const float* W2       = (const float*)d_in[14];
  const float* b2       = (const float*)d_in[15];
  const float* cls_w1   = (const float*)d_in[16];
  const float* cls_b1   = (const float*)d_in[17];
  const float* cls_w2   = (const float*)d_in[18];
  const float* cls_b2   = (const float*)d_in[19];

  float* out_logits = (float*)d_out;                   // [B, C]
  float* out_gw     = (float*)d_out + (size_t)B_ * C_; // [B, P]

  // workspace layout (bytes)
  char* ws = (char*)d_ws;
  int*   cnt     = (int*)(ws + 0);                 // 512
  int*   gindex  = (int*)(ws + 512);               // 2,048,000
  int*   sel_idx = (int*)(ws + 2048512);           // 3072
  float* sel_w   = (float*)(ws + 2051584);         // 3072
  float* hpart   = (float*)(ws + 2054656);         // 1,048,576
  unsigned short* wcomp = (unsigned short*)(ws + 3103232); // 31,457,280
  float* hpart2  = (float*)(ws + 34560512);        // 1536*64*4 = 393,216

  hipLaunchKernelGGL(k_pre, dim3(P_ + 256), dim3(512), 0, stream,
                     gene_mask, x_rna, gate_w1, W1, cnt, gindex, wcomp, hpart);
  hipLaunchKernelGGL(k_gate2, dim3(B_), dim3(128), 0, stream,
                     hpart, gate_b1, gate_w2, gate_b2, out_gw, sel_idx, sel_w);
  hipLaunchKernelGGL(k_expert, dim3(B_ * K_ * 2), dim3(512), 0, stream,
                     x_rna, x_cnv, x_met, W1, cnt, gindex, wcomp, sel_idx,
                     hpart2);
  hipLaunchKernelGGL(k_final2, dim3(B_), dim3(192), 0, stream,
                     hpart2, sel_idx, sel_w, b1, bn_g, bn_b, bn_m, bn_v,
                     W2, b2, cls_w1, cls_b1, cls_w2, cls_b2, out_logits);
}